// Round 11
// baseline (563.668 us; speedup 1.0000x reference)
//
#include <hip/hip_runtime.h>
#include <stdint.h>

#define NB   16
#define CIN  512
#define COUT 512
#define HH   64
#define WW   64
#define NCOND 512
#define TAPS 9
#define EPSD 1e-8f

typedef short bf16x8 __attribute__((ext_vector_type(8)));
typedef float f32x4 __attribute__((ext_vector_type(4)));
typedef float f32x16 __attribute__((ext_vector_type(16)));

static __device__ __forceinline__ short f2bf(float f) {
  union { float f; uint32_t u; } c;
  c.f = f;
  uint32_t u = c.u;
  uint32_t r = (u + 0x7FFFu + ((u >> 16) & 1u)) >> 16;
  return (short)(uint16_t)r;
}

static __device__ __forceinline__ void gl_lds16(const void* g, void* l) {
  __builtin_amdgcn_global_load_lds(
      (const __attribute__((address_space(1))) void*)g,
      (__attribute__((address_space(3))) void*)l, 16, 0, 0);
}

// ---------------- k1: gamma[b,i] = b_gamma[i] + sum_c y[b,c]*w_gamma[i,c] ----
__global__ __launch_bounds__(512) void k_gamma(const float* __restrict__ y,
                                               const float* __restrict__ w_gamma,
                                               const float* __restrict__ b_gamma,
                                               float* __restrict__ gamma,
                                               float* __restrict__ zbuf) {
  __shared__ float ys[NCOND];
  const int b = blockIdx.x;
  const int i = threadIdx.x;
  if (zbuf && b == 0) { zbuf[i] = 0.f; zbuf[i + 512] = 0.f; }  // 4KB zeros
  ys[i] = y[b * NCOND + i];
  __syncthreads();
  const float4* wg = reinterpret_cast<const float4*>(w_gamma + (size_t)i * NCOND);
  float acc = b_gamma[i];
  for (int c4 = 0; c4 < NCOND / 4; ++c4) {
    float4 w4 = wg[c4];
    acc += w4.x * ys[c4 * 4 + 0] + w4.y * ys[c4 * 4 + 1] +
           w4.z * ys[c4 * 4 + 2] + w4.w * ys[c4 * 4 + 3];
  }
  gamma[b * CIN + i] = acc;
}

// ------- k_prep2: s2 + W2[chunk][tap][cout][cin32], 16B-slot pre-swizzled ----
__global__ __launch_bounds__(256) void k_prep2(const float* __restrict__ w_conv,
                                               float* __restrict__ s2,
                                               short* __restrict__ W2) {
  __shared__ float ws_s[CIN * TAPS];
  const int o = blockIdx.x;
  const int t = threadIdx.x;
  const float* wsrc = w_conv + (size_t)o * CIN * TAPS;
  for (int idx = t; idx < CIN * TAPS; idx += 256) ws_s[idx] = wsrc[idx];
  __syncthreads();
  for (int i = t; i < CIN; i += 256) {
    float s = 0.f;
#pragma unroll
    for (int tap = 0; tap < TAPS; ++tap) {
      float v = ws_s[i * TAPS + tap];
      s += v * v;
    }
    s2[(size_t)o * CIN + i] = s;
  }
  const int key = (o >> 1) & 3;
  for (int k = t; k < CIN * TAPS; k += 256) {
    int tap = k >> 9;       // 0..8
    int r = k & 511;        // cin index i
    int c = r >> 5, sl = (r >> 3) & 3, j = r & 7;
    W2[((size_t)(c * TAPS + tap) * COUT + o) * 32 + ((sl ^ key) * 8) + j] =
        f2bf(ws_s[r * TAPS + tap]);
  }
}

// ---- k_prep (old layout, fallback path): Wr[o][tap][i] --------------------
__global__ __launch_bounds__(256) void k_prep(const float* __restrict__ w_conv,
                                              float* __restrict__ s2,
                                              short* __restrict__ Wr) {
  __shared__ float ws_s[CIN * TAPS];
  const int o = blockIdx.x;
  const int t = threadIdx.x;
  const float* wsrc = w_conv + (size_t)o * CIN * TAPS;
  for (int idx = t; idx < CIN * TAPS; idx += 256) ws_s[idx] = wsrc[idx];
  __syncthreads();
  for (int i = t; i < CIN; i += 256) {
    float s = 0.f;
#pragma unroll
    for (int tap = 0; tap < TAPS; ++tap) {
      float v = ws_s[i * TAPS + tap];
      s += v * v;
    }
    s2[(size_t)o * CIN + i] = s;
  }
  for (int idx = t; idx < CIN * TAPS; idx += 256) {
    int i = idx & (CIN - 1);
    int tap = idx >> 9;
    Wr[((size_t)o * TAPS + tap) * CIN + i] = f2bf(ws_s[i * TAPS + tap]);
  }
}

// ---------------- k3: d[b,o] = rsqrt(sum_i gamma^2 * s2 + eps) ---------------
__global__ __launch_bounds__(512) void k_d(const float* __restrict__ gamma,
                                           const float* __restrict__ s2,
                                           float* __restrict__ dscale) {
  __shared__ float g2[CIN];
  const int b = blockIdx.x;
  const int o = threadIdx.x;
  float g = gamma[b * CIN + o];
  g2[o] = g * g;
  __syncthreads();
  const float4* s4 = reinterpret_cast<const float4*>(s2 + (size_t)o * CIN);
  float acc = 0.f;
  for (int i4 = 0; i4 < CIN / 4; ++i4) {
    float4 v = s4[i4];
    acc += v.x * g2[i4 * 4 + 0] + v.y * g2[i4 * 4 + 1] +
           v.z * g2[i4 * 4 + 2] + v.w * g2[i4 * 4 + 3];
  }
  dscale[b * COUT + o] = rsqrtf(acc + EPSD);
}

// -- k_xmod2: xm[b][y][w][cin] bf16 modulated, 16B-slot pre-swizzled by w -----
__global__ __launch_bounds__(256) void k_xmod2(const float* __restrict__ x,
                                               const float* __restrict__ gamma,
                                               short* __restrict__ xm) {
  __shared__ float tile[64][67];
  __shared__ float gs[CIN];
  const int y = blockIdx.x, b = blockIdx.y;
  const int t = threadIdx.x;
  gs[t] = gamma[b * CIN + t];
  gs[t + 256] = gamma[b * CIN + t + 256];
  __syncthreads();
  const int w = t >> 2, q = t & 3;
  const int sw = (w >> 1) & 3;
  short* dst = xm + (((size_t)b * HH + y) * WW + w) * CIN;
  for (int c0 = 0; c0 < CIN; c0 += 64) {
    {
      int ww_ = t & 63;
      int cb = t >> 6;  // 0..3
      const float* xp = x + (((size_t)(b * CIN + c0 + cb)) * HH + y) * WW + ww_;
#pragma unroll
      for (int p = 0; p < 16; ++p)
        tile[cb + p * 4][ww_] = xp[(size_t)p * 4 * HH * WW];
    }
    __syncthreads();
#pragma unroll
    for (int h = 0; h < 2; ++h) {
      int c_lo = q * 16 + h * 8;
      int chunk = (c0 + c_lo) >> 5;
      int sl = (c_lo >> 3) & 3;
      short tmp[8];
#pragma unroll
      for (int j = 0; j < 8; ++j)
        tmp[j] = f2bf(tile[c_lo + j][w] * gs[c0 + c_lo + j]);
      *reinterpret_cast<bf16x8*>(dst + chunk * 32 + (sl ^ sw) * 8) =
          *reinterpret_cast<const bf16x8*>(tmp);
    }
    __syncthreads();
  }
}

// ---------------- k_conv9: 32x32x16-MFMA, A-from-global conv -----------------
// grid 512 = ot(2) x b(16) x sp(16), XCD-chunked. 512 thr = 8 waves (2Mx4N).
// Block tile 256 cout x 256 px (4 rows). Wave tile 128 cout x 64 px (1 row),
// 4 mt x 2 nt tiles of 32x32, K=32 as 2 halves of 16.
// A global->VGPR dbuf 1 tap ahead; X in LDS dbuf (staged at tp7).
// One barrier per chunk, counted vmcnt(8).
__global__ __launch_bounds__(512, 2) void k_conv9(const short* __restrict__ xm,
                                                  const short* __restrict__ W2,
                                                  const short* __restrict__ zbuf,
                                                  const float* __restrict__ dscale,
                                                  float* __restrict__ out) {
  __shared__ short Xs[2 * 6 * 64 * 32]; // 48KB (6 rowblocks x 64w x 32c) x 2
  __shared__ float d_s[256];
  __shared__ __align__(64) short zls[64];  // 128B LDS zero page

  const int orig = blockIdx.x;
  const int wgid = ((orig & 7) << 6) | (orig >> 3);  // 512 % 8 == 0, bijective
  const int ot = wgid >> 8;        // 0..1  (cout 256-half)
  const int b  = (wgid >> 4) & 15;
  const int sp = wgid & 15;        // output rows 4sp..4sp+3

  const int t = threadIdx.x, lane = t & 63;
  const int wv = t >> 6;           // 0..7
  const int wr = wv >> 2;          // 0..1 : cout 128-half within tile
  const int wc = wv & 3;           // 0..3 : output row within strip
  const int l31 = lane & 31;
  const int k8 = lane >> 5;        // k-half 0/1

  if (t < 256) d_s[t] = dscale[b * COUT + ot * 256 + t];
  if (t < 64) zls[t] = 0;

  // ---- X staging sources (3 gl_lds per thread, 512 thr) ----
  const short* xS[3];
#pragma unroll
  for (int i = 0; i < 3; ++i) {
    int idx = t + 512 * i;
    int rb = idx >> 8;             // 0..5
    int w = (idx & 255) >> 2;
    int sl = idx & 3;
    int ysrc = sp * 4 + rb - 1;
    bool rv = (ysrc >= 0) && (ysrc < HH);
    xS[i] = rv ? xm + (((size_t)b * HH + ysrc) * WW + w) * CIN + sl * 8
               : zbuf + sl * 8;    // zbuf: 2048 zero shorts
  }

  // ---- A per-lane global bases (32x32x16 frag: o = oL + mt*32, k-half k8) ---
  const int oL = ot * 256 + wr * 128 + l31;
  const int key0 = (oL >> 1) & 3;  // invariant across mt (mt*16 == 0 mod 4)
  const short* aC0 = W2 + (size_t)oL * 32 + (((0 * 2 + k8) ^ key0) * 8);
  const short* aC1 = W2 + (size_t)oL * 32 + (((1 * 2 + k8) ^ key0) * 8);

  // ---- X read bases: p[nt][dxi] at pixel w = nt*32 + l31 + dxi-1 ----------
  // kk=0 slot = k8^kw at <<4; kk=1 = slot^2 -> addr ^ 0x20.
  const char* pb[2][3];
#pragma unroll
  for (int nt = 0; nt < 2; ++nt) {
#pragma unroll
    for (int dxi = 0; dxi < 3; ++dxi) {
      int w = nt * 32 + l31 + dxi - 1;   // -1..64 (invalids masked at use)
      int kw = (w >> 1) & 3;
      pb[nt][dxi] = (const char*)&Xs[0] + w * 64 + ((k8 ^ kw) << 4);
    }
  }
  char* wx0 = (char*)&Xs[0] + t * 16;
  const char* zl = (const char*)&zls[0];
  const bool mL = (l31 == 0);   // (nt=0, dx=-1) invalid pixel -1
  const bool mR = (l31 == 31);  // (nt=1, dx=+1) invalid pixel 64

  f32x16 acc[4][2];
#pragma unroll
  for (int mt = 0; mt < 4; ++mt)
#pragma unroll
    for (int nt = 0; nt < 2; ++nt)
#pragma unroll
      for (int r = 0; r < 16; ++r)
        acc[mt][nt][r] = 0.f;

  bf16x8 aA[8], aB[8];  // [kk*4+mt]

  // ---- prologue: X chunk 0 + A frags for step 0 ----
#pragma unroll
  for (int i = 0; i < 3; ++i)
    gl_lds16(xS[i], wx0 + i * 8192);
#pragma unroll
  for (int mt = 0; mt < 4; ++mt) {
    aA[mt]     = *reinterpret_cast<const bf16x8*>(aC0 + mt * 1024);
    aA[4 + mt] = *reinterpret_cast<const bf16x8*>(aC1 + mt * 1024);
  }
  asm volatile("s_waitcnt vmcnt(0) lgkmcnt(0)" ::: "memory");
  __builtin_amdgcn_s_barrier();
  asm volatile("" ::: "memory");

#define LD8(p) (*reinterpret_cast<const bf16x8*>(p))
#define X32(p) ((const char*)(((uintptr_t)(p)) ^ 32))

#define DO_TAP(tp, CUR, NXT, STGX, KNV)                                       \
  {                                                                           \
    _Pragma("unroll") for (int mt_ = 0; mt_ < 4; ++mt_) {                     \
      NXT[mt_]     = LD8(aC0 + ((tp) + 1) * 16384 + mt_ * 1024);              \
      NXT[4 + mt_] = LD8(aC1 + ((tp) + 1) * 16384 + mt_ * 1024);              \
    }                                                                         \
    if (STGX) {                                                               \
      _Pragma("unroll") for (int i_ = 0; i_ < 3; ++i_)                        \
          gl_lds16(xS[i_] + (KNV), wxw + i_ * 8192);                          \
    }                                                                         \
    __builtin_amdgcn_sched_barrier(0);                                        \
    {                                                                         \
      const int dy_ = (tp) / 3 - 1, dx_ = (tp) % 3 - 1;                       \
      const int rbo_ = (wc + dy_ + 1) * 4096;                                 \
      const char* s0_ = ((dx_ == -1) && mL) ? (zl - rbo_) : q0[dx_ + 1];      \
      const char* s1_ = ((dx_ == 1) && mR) ? (zl - rbo_) : q1[dx_ + 1];       \
      bf16x8 bfr[4];                                                          \
      bfr[0] = LD8(s0_ + rbo_);                                               \
      bfr[1] = LD8(X32(s0_ + rbo_));                                          \
      bfr[2] = LD8(s1_ + rbo_);                                               \
      bfr[3] = LD8(X32(s1_ + rbo_));                                          \
      __builtin_amdgcn_s_setprio(1);                                          \
      _Pragma("unroll") for (int mt_ = 0; mt_ < 4; ++mt_)                     \
        _Pragma("unroll") for (int nt_ = 0; nt_ < 2; ++nt_) {                 \
          acc[mt_][nt_] = __builtin_amdgcn_mfma_f32_32x32x16_bf16(            \
              CUR[mt_], bfr[nt_ * 2], acc[mt_][nt_], 0, 0, 0);                \
          acc[mt_][nt_] = __builtin_amdgcn_mfma_f32_32x32x16_bf16(            \
              CUR[4 + mt_], bfr[nt_ * 2 + 1], acc[mt_][nt_], 0, 0, 0);        \
        }                                                                     \
      __builtin_amdgcn_s_setprio(0);                                          \
    }                                                                         \
  }

#define CHUNK_TAPS(A0, A1, KNV)                                               \
  DO_TAP(0, A0, A1, false, 0)                                                 \
  DO_TAP(1, A1, A0, false, 0)                                                 \
  DO_TAP(2, A0, A1, false, 0)                                                 \
  DO_TAP(3, A1, A0, false, 0)                                                 \
  DO_TAP(4, A0, A1, false, 0)                                                 \
  DO_TAP(5, A1, A0, false, 0)                                                 \
  DO_TAP(6, A0, A1, false, 0)                                                 \
  DO_TAP(7, A1, A0, true, KNV)                                                \
  DO_TAP(8, A0, A1, false, 0)                                                 \
  __builtin_amdgcn_sched_barrier(0);                                          \
  asm volatile("s_waitcnt vmcnt(8)" ::: "memory");                            \
  __builtin_amdgcn_s_barrier();                                               \
  asm volatile("" ::: "memory");

  for (int c2 = 0; c2 < 8; ++c2) {
    // even chunk: read X buf 0, stage into buf 1
    {
      const char* q0[3] = {pb[0][0], pb[0][1], pb[0][2]};
      const char* q1[3] = {pb[1][0], pb[1][1], pb[1][2]};
      char* wxw = wx0 + 24576;
      const int knv = (2 * c2 + 1) * 32;
      CHUNK_TAPS(aA, aB, knv)
    }
    aC0 += 9 * 16384;
    aC1 += 9 * 16384;
    // odd chunk: read X buf 1, stage into buf 0
    {
      const char* q0[3] = {pb[0][0] + 24576, pb[0][1] + 24576, pb[0][2] + 24576};
      const char* q1[3] = {pb[1][0] + 24576, pb[1][1] + 24576, pb[1][2] + 24576};
      char* wxw = wx0;
      const int knv = (c2 < 7) ? (2 * c2 + 2) * 32 : 0;
      CHUNK_TAPS(aB, aA, knv)
    }
    aC0 += 9 * 16384;
    aC1 += 9 * 16384;
  }
#undef CHUNK_TAPS
#undef DO_TAP
#undef X32
#undef LD8

  // ---- epilogue: out = d[b,o] * acc (32x32 C/D: row=(r&3)+8(r>>2)+4*k8,
  //      col=l31) ----
#pragma unroll
  for (int mt = 0; mt < 4; ++mt) {
#pragma unroll
    for (int nt = 0; nt < 2; ++nt) {
#pragma unroll
      for (int r = 0; r < 16; ++r) {
        int row = (r & 3) + 8 * (r >> 2) + 4 * k8;
        int o_l = wr * 128 + mt * 32 + row;
        int o = ot * 256 + o_l;
        int yy = sp * 4 + wc;
        int px = nt * 32 + l31;
        out[(((size_t)b * COUT + o) * HH + yy) * WW + px] = d_s[o_l] * acc[mt][nt][r];
      }
    }
  }
}

// ---------------- fallback conv (round-1 kernel) for small ws ----------------
__global__ __launch_bounds__(256) void k_conv_fb(const float* __restrict__ x,
                                                 const short* __restrict__ Wr,
                                                 const float* __restrict__ gamma,
                                                 const float* __restrict__ dscale,
                                                 float* __restrict__ out) {
  __shared__ short As[128 * 64];
  __shared__ short Xs[4 * 64 * 64];
  __shared__ float gam_s[CIN];
  __shared__ float d_s[128];

  const int sp = blockIdx.x;
  const int ot = blockIdx.y;
  const int b  = blockIdx.z;
  const int t  = threadIdx.x;
  const int lane = t & 63;
  const int wv = t >> 6;
  const int wr = wv >> 1;
  const int wc = wv & 1;

  gam_s[t] = gamma[b * CIN + t];
  gam_s[t + 256] = gamma[b * CIN + t + 256];
  if (t < 128) d_s[t] = dscale[b * COUT + ot * 128 + t];

  f32x4 acc[4][4];
#pragma unroll
  for (int m = 0; m < 4; ++m)
#pragma unroll
    for (int n = 0; n < 4; ++n)
      acc[m][n] = (f32x4){0.f, 0.f, 0.f, 0.f};

  const int srow = t >> 6;
  const int sc = t & 63;
  const int ysrc = sp * 2 + srow - 1;
  const bool rv = (ysrc >= 0) && (ysrc < HH);
  const int ycl = rv ? ysrc : 0;
  const float* xrow = x + (((size_t)b * CIN) * HH + ycl) * WW + sc;
  short* xs_base = &Xs[(srow * 64 + sc) * 64];
  const int xs_sw = (sc & 7) << 4;

  for (int chunk = 0; chunk < CIN / 64; ++chunk) {
    const int i0 = chunk * 64;
    __syncthreads();
    {
      const float* xp = xrow + (size_t)i0 * (HH * WW);
#pragma unroll
      for (int i8 = 0; i8 < 8; ++i8) {
        short tmp[8];
#pragma unroll
        for (int j = 0; j < 8; ++j) {
          int i = i8 * 8 + j;
          float v = rv ? xp[i * (HH * WW)] : 0.0f;
          tmp[j] = f2bf(v * gam_s[i0 + i]);
        }
        char* dst = (char*)xs_base + ((i8 * 16) ^ xs_sw);
        *reinterpret_cast<bf16x8*>(dst) = *reinterpret_cast<const bf16x8*>(tmp);
      }
    }
    for (int tap = 0; tap < TAPS; ++tap) {
      __syncthreads();
#pragma unroll
      for (int j = 0; j < 4; ++j) {
        int s = t + 256 * j;
        int row = s >> 3, sl = s & 7;
        int kbyte = (sl * 16) ^ ((row & 7) << 4);
        const short* src = Wr + ((size_t)(ot * 128 + row) * TAPS + tap) * CIN +
                           i0 + (kbyte >> 1);
        *reinterpret_cast<bf16x8*>((char*)As + row * 128 + sl * 16) =
            *reinterpret_cast<const bf16x8*>(src);
      }
      __syncthreads();

      const int dy = tap / 3 - 1, dx = tap % 3 - 1;
      bf16x8 afr[2][4], bfr[2][4];
#pragma unroll
      for (int kk = 0; kk < 2; ++kk) {
        const int kb = kk * 64 + (lane >> 4) * 16;
#pragma unroll
        for (int m = 0; m < 4; ++m) {
          int row = wr * 64 + m * 16 + (lane & 15);
          afr[kk][m] = *reinterpret_cast<const bf16x8*>(
              (const char*)As + row * 128 + (kb ^ ((row & 7) << 4)));
        }
#pragma unroll
        for (int n = 0; n < 4; ++n) {
          int p = wc * 64 + n * 16 + (lane & 15);
          int r = p >> 6, c = p & 63;
          int cc = c + dx;
          bool val = (cc >= 0) && (cc < WW);
          int ccl = val ? cc : 0;
          int rr = r + dy + 1;
          bf16x8 f = *reinterpret_cast<const bf16x8*>(
              (const char*)Xs + (rr * 64 + ccl) * 128 + (kb ^ ((ccl & 7) << 4)));
          if (!val) f = (bf16x8){0, 0, 0, 0, 0, 0, 0, 0};
          bfr[kk][n] = f;
        }
      }
#pragma unroll
      for (int m = 0; m < 4; ++m)
#pragma unroll
        for (int n = 0; n < 4; ++n)
#pragma unroll
          for (int kk = 0; kk < 2; ++kk)
            acc[m][n] = __builtin_amdgcn_mfma_f32_16x16x32_bf16(
                afr[kk][m], bfr[kk][n], acc[m][n], 0, 0, 0);
    }
  }

#pragma unroll
  for (int m = 0; m < 4; ++m) {
#pragma unroll
    for (int n = 0; n < 4; ++n) {
#pragma unroll
      for (int j = 0; j < 4; ++j) {
        int o_l = wr * 64 + m * 16 + (lane >> 4) * 4 + j;
        int o = ot * 128 + o_l;
        int p = wc * 64 + n * 16 + (lane & 15);
        int yy = sp * 2 + (p >> 6);
        int cx = p & 63;
        out[(((size_t)b * COUT + o) * HH + yy) * WW + cx] = d_s[o_l] * acc[m][n][j];
      }
    }
  }
}

extern "C" void kernel_launch(void* const* d_in, const int* in_sizes, int n_in,
                              void* d_out, int out_size, void* d_ws, size_t ws_size,
                              hipStream_t stream) {
  const float* x = (const float*)d_in[0];
  const float* y = (const float*)d_in[1];
  const float* w_conv = (const float*)d_in[2];
  const float* w_gamma = (const float*)d_in[3];
  const float* b_gamma = (const float*)d_in[4];
  float* out = (float*)d_out;

  char* ws = (char*)d_ws;
  short* W2 = (short*)ws;                        // 4,718,592 B (+131K pad)
  float* gamma = (float*)(ws + 4849664);         // 32,768 B
  float* dsc = (float*)(ws + 4882432);           // 32,768 B
  float* s2 = (float*)(ws + 4915200);            // 1,048,576 B
  char* zbuf = ws + 5963776;                     // 4,096 B zero page
  short* xm = (short*)(ws + 5967872);            // 67,108,864 B
  const size_t NEED = 5967872 + (size_t)NB * HH * WW * CIN * 2 + 4096;

  const bool fast = ws_size >= NEED;

  if (fast) {
    hipLaunchKernelGGL(k_gamma, dim3(NB), dim3(512), 0, stream, y, w_gamma,
                       b_gamma, gamma, (float*)zbuf);
    hipLaunchKernelGGL(k_prep2, dim3(COUT), dim3(256), 0, stream, w_conv, s2, W2);
    hipLaunchKernelGGL(k_d, dim3(NB), dim3(512), 0, stream, gamma, s2, dsc);
    hipLaunchKernelGGL(k_xmod2, dim3(HH, NB), dim3(256), 0, stream, x, gamma, xm);
    hipLaunchKernelGGL(k_conv9, dim3(512), dim3(512), 0, stream, xm, W2,
                       (const short*)zbuf, dsc, out);
  } else {
    hipLaunchKernelGGL(k_gamma, dim3(NB), dim3(512), 0, stream, y, w_gamma,
                       b_gamma, gamma, (float*)nullptr);
    hipLaunchKernelGGL(k_prep, dim3(COUT), dim3(256), 0, stream, w_conv, s2, W2);
    hipLaunchKernelGGL(k_d, dim3(NB), dim3(512), 0, stream, gamma, s2, dsc);
    hipLaunchKernelGGL(k_conv_fb, dim3(32, 4, NB), dim3(256), 0, stream, x, W2,
                       gamma, dsc, out);
  }
}

// Round 12
// 402.272 us; speedup vs baseline: 1.4012x; 1.4012x over previous
//
#include <hip/hip_runtime.h>
#include <stdint.h>

#define NB   16
#define CIN  512
#define COUT 512
#define HH   64
#define WW   64
#define NCOND 512
#define TAPS 9
#define EPSD 1e-8f

typedef short bf16x8 __attribute__((ext_vector_type(8)));
typedef float f32x4 __attribute__((ext_vector_type(4)));

static __device__ __forceinline__ short f2bf(float f) {
  union { float f; uint32_t u; } c;
  c.f = f;
  uint32_t u = c.u;
  uint32_t r = (u + 0x7FFFu + ((u >> 16) & 1u)) >> 16;
  return (short)(uint16_t)r;
}

static __device__ __forceinline__ void gl_lds16(const void* g, void* l) {
  __builtin_amdgcn_global_load_lds(
      (const __attribute__((address_space(1))) void*)g,
      (__attribute__((address_space(3))) void*)l, 16, 0, 0);
}

// ---------------- k1 (fallback): gamma ---------------------------------------
__global__ __launch_bounds__(512) void k_gamma(const float* __restrict__ y,
                                               const float* __restrict__ w_gamma,
                                               const float* __restrict__ b_gamma,
                                               float* __restrict__ gamma,
                                               float* __restrict__ zbuf) {
  __shared__ float ys[NCOND];
  const int b = blockIdx.x;
  const int i = threadIdx.x;
  if (zbuf && b == 0) { zbuf[i] = 0.f; zbuf[i + 512] = 0.f; }
  ys[i] = y[b * NCOND + i];
  __syncthreads();
  const float4* wg = reinterpret_cast<const float4*>(w_gamma + (size_t)i * NCOND);
  float acc = b_gamma[i];
  for (int c4 = 0; c4 < NCOND / 4; ++c4) {
    float4 w4 = wg[c4];
    acc += w4.x * ys[c4 * 4 + 0] + w4.y * ys[c4 * 4 + 1] +
           w4.z * ys[c4 * 4 + 2] + w4.w * ys[c4 * 4 + 3];
  }
  gamma[b * CIN + i] = acc;
}

// ---------------- k_gd: fused gamma + demod scale ----------------------------
__global__ __launch_bounds__(512) void k_gd(const float* __restrict__ y,
                                            const float* __restrict__ w_gamma,
                                            const float* __restrict__ b_gamma,
                                            const float* __restrict__ s2,
                                            float* __restrict__ gamma,
                                            float* __restrict__ dscale,
                                            float* __restrict__ zbuf) {
  __shared__ float ys[NCOND];
  __shared__ float g2[CIN];
  const int b = blockIdx.x;
  const int i = threadIdx.x;
  if (b == 0) { zbuf[i] = 0.f; zbuf[i + 512] = 0.f; }  // 4KB zeros
  ys[i] = y[b * NCOND + i];
  __syncthreads();
  const float4* wg = reinterpret_cast<const float4*>(w_gamma + (size_t)i * NCOND);
  float acc = b_gamma[i];
  for (int c4 = 0; c4 < NCOND / 4; ++c4) {
    float4 w4 = wg[c4];
    acc += w4.x * ys[c4 * 4 + 0] + w4.y * ys[c4 * 4 + 1] +
           w4.z * ys[c4 * 4 + 2] + w4.w * ys[c4 * 4 + 3];
  }
  gamma[b * CIN + i] = acc;
  g2[i] = acc * acc;
  __syncthreads();
  const float4* s4 = reinterpret_cast<const float4*>(s2 + (size_t)i * CIN);
  float a2 = 0.f;
  for (int c4 = 0; c4 < CIN / 4; ++c4) {
    float4 v = s4[c4];
    a2 += v.x * g2[c4 * 4 + 0] + v.y * g2[c4 * 4 + 1] +
          v.z * g2[c4 * 4 + 2] + v.w * g2[c4 * 4 + 3];
  }
  dscale[b * COUT + i] = rsqrtf(a2 + EPSD);
}

// ------- k_prep2: s2 + W2[chunk][tap][cout][cin32], 16B-slot pre-swizzled ----
__global__ __launch_bounds__(256) void k_prep2(const float* __restrict__ w_conv,
                                               float* __restrict__ s2,
                                               short* __restrict__ W2) {
  __shared__ float ws_s[CIN * TAPS];
  const int o = blockIdx.x;
  const int t = threadIdx.x;
  const float* wsrc = w_conv + (size_t)o * CIN * TAPS;
  for (int idx = t; idx < CIN * TAPS; idx += 256) ws_s[idx] = wsrc[idx];
  __syncthreads();
  for (int i = t; i < CIN; i += 256) {
    float s = 0.f;
#pragma unroll
    for (int tap = 0; tap < TAPS; ++tap) {
      float v = ws_s[i * TAPS + tap];
      s += v * v;
    }
    s2[(size_t)o * CIN + i] = s;
  }
  const int key = (o >> 1) & 3;
  for (int k = t; k < CIN * TAPS; k += 256) {
    int tap = k >> 9;
    int r = k & 511;
    int c = r >> 5, sl = (r >> 3) & 3, j = r & 7;
    W2[((size_t)(c * TAPS + tap) * COUT + o) * 32 + ((sl ^ key) * 8) + j] =
        f2bf(ws_s[r * TAPS + tap]);
  }
}

// ---- k_prep (fallback layout): Wr[o][tap][i] --------------------------------
__global__ __launch_bounds__(256) void k_prep(const float* __restrict__ w_conv,
                                              float* __restrict__ s2,
                                              short* __restrict__ Wr) {
  __shared__ float ws_s[CIN * TAPS];
  const int o = blockIdx.x;
  const int t = threadIdx.x;
  const float* wsrc = w_conv + (size_t)o * CIN * TAPS;
  for (int idx = t; idx < CIN * TAPS; idx += 256) ws_s[idx] = wsrc[idx];
  __syncthreads();
  for (int i = t; i < CIN; i += 256) {
    float s = 0.f;
#pragma unroll
    for (int tap = 0; tap < TAPS; ++tap) {
      float v = ws_s[i * TAPS + tap];
      s += v * v;
    }
    s2[(size_t)o * CIN + i] = s;
  }
  for (int idx = t; idx < CIN * TAPS; idx += 256) {
    int i = idx & (CIN - 1);
    int tap = idx >> 9;
    Wr[((size_t)o * TAPS + tap) * CIN + i] = f2bf(ws_s[i * TAPS + tap]);
  }
}

// ---------------- k3 (fallback): d -------------------------------------------
__global__ __launch_bounds__(512) void k_d(const float* __restrict__ gamma,
                                           const float* __restrict__ s2,
                                           float* __restrict__ dscale) {
  __shared__ float g2[CIN];
  const int b = blockIdx.x;
  const int o = threadIdx.x;
  float g = gamma[b * CIN + o];
  g2[o] = g * g;
  __syncthreads();
  const float4* s4 = reinterpret_cast<const float4*>(s2 + (size_t)o * CIN);
  float acc = 0.f;
  for (int i4 = 0; i4 < CIN / 4; ++i4) {
    float4 v = s4[i4];
    acc += v.x * g2[i4 * 4 + 0] + v.y * g2[i4 * 4 + 1] +
           v.z * g2[i4 * 4 + 2] + v.w * g2[i4 * 4 + 3];
  }
  dscale[b * COUT + o] = rsqrtf(acc + EPSD);
}

// -- k_xmod2: xm[b][y][w][cin] bf16 modulated, 16B-slot pre-swizzled by w -----
__global__ __launch_bounds__(256) void k_xmod2(const float* __restrict__ x,
                                               const float* __restrict__ gamma,
                                               short* __restrict__ xm) {
  __shared__ float tile[64][67];
  __shared__ float gs[CIN];
  const int y = blockIdx.x, b = blockIdx.y;
  const int t = threadIdx.x;
  gs[t] = gamma[b * CIN + t];
  gs[t + 256] = gamma[b * CIN + t + 256];
  __syncthreads();
  const int w = t >> 2, q = t & 3;
  const int sw = (w >> 1) & 3;
  short* dst = xm + (((size_t)b * HH + y) * WW + w) * CIN;
  for (int c0 = 0; c0 < CIN; c0 += 64) {
    {
      int ww_ = t & 63;
      int cb = t >> 6;
      const float* xp = x + (((size_t)(b * CIN + c0 + cb)) * HH + y) * WW + ww_;
#pragma unroll
      for (int p = 0; p < 16; ++p)
        tile[cb + p * 4][ww_] = xp[(size_t)p * 4 * HH * WW];
    }
    __syncthreads();
#pragma unroll
    for (int h = 0; h < 2; ++h) {
      int c_lo = q * 16 + h * 8;
      int chunk = (c0 + c_lo) >> 5;
      int sl = (c_lo >> 3) & 3;
      short tmp[8];
#pragma unroll
      for (int j = 0; j < 8; ++j)
        tmp[j] = f2bf(tile[c_lo + j][w] * gs[c0 + c_lo + j]);
      *reinterpret_cast<bf16x8*>(dst + chunk * 32 + (sl ^ sw) * 8) =
          *reinterpret_cast<const bf16x8*>(tmp);
    }
    __syncthreads();
  }
}

// ---------------- k_conv10: v7 + register fragment double-buffer -------------
// grid 512, 512 thr = 8 waves (2Mx4N). Block tile 256x256px; wave 128x64.
// A: LDS ring-4 (stage dist 3). X: LDS dbuf (staged tp7). Fragments for tap
// t+1 ds_read during tap t's MFMA cluster (reg dbuf fa0/fb0 <-> fa1/fb1).
// Waits: lgkm(12) [cur frags oldest-12], vmcnt(2|5), 1 barrier/tap.
__global__ __launch_bounds__(512, 1) void k_conv10(const short* __restrict__ xm,
                                                   const short* __restrict__ W2,
                                                   const short* __restrict__ zbuf,
                                                   const float* __restrict__ dscale,
                                                   float* __restrict__ out) {
  __shared__ short As[4 * 256 * 32];    // 64KB ring of 4 panels
  __shared__ short Xs[2 * 6 * 64 * 32]; // 48KB x-dbuf
  __shared__ float d_s[256];
  __shared__ __align__(16) short zls[64];

  const int orig = blockIdx.x;
  const int wgid = ((orig & 7) << 6) | (orig >> 3);
  const int ot = wgid >> 8;
  const int b  = (wgid >> 4) & 15;
  const int sp = wgid & 15;

  const int t = threadIdx.x, lane = t & 63;
  const int wv = t >> 6;
  const int wr = wv >> 2;
  const int wc = wv & 3;
  const int l15 = lane & 15;
  const int kb0 = (lane >> 4) << 4;

  if (t < 256) d_s[t] = dscale[b * COUT + ot * 256 + t];
  if (t < 64) zls[t] = 0;

  const short* aS0 = W2 + (size_t)(ot * 256 + (t >> 2)) * 32 + (t & 3) * 8;
  const short* aS1 = aS0 + 128 * 32;
  const short* xS[3];
#pragma unroll
  for (int i = 0; i < 3; ++i) {
    int idx = t + 512 * i;
    int rb = idx >> 8;
    int w = (idx & 255) >> 2;
    int sl = idx & 3;
    int ysrc = sp * 4 + rb - 1;
    bool rv = (ysrc >= 0) && (ysrc < HH);
    xS[i] = rv ? xm + (((size_t)b * HH + ysrc) * WW + w) * CIN + sl * 8
               : zbuf + sl * 8;
  }

  const char* pa0 = (const char*)&As[0] + (wr * 128 + l15) * 64 +
                    (kb0 ^ (((l15 >> 1) & 3) << 4));
  const char* paR[4];
  char* waR[4];
#pragma unroll
  for (int i = 0; i < 4; ++i) {
    paR[i] = pa0 + i * 16384;
    waR[i] = (char*)&As[0] + t * 16 + i * 16384;
  }
  const char* pbx[3];
#pragma unroll
  for (int dxi = 0; dxi < 3; ++dxi) {
    int lcc = l15 + dxi - 1;             // signed, v6/v7-verified
    int key = (lcc >> 1) & 3;
    pbx[dxi] = (const char*)&Xs[0] + lcc * 64 + (kb0 ^ (key << 4));
  }
  const int lc3 = (l15 + 1 > 15) ? 15 : (l15 + 1);
  const char* pbx3 = (const char*)&Xs[0] + lc3 * 64 + (kb0 ^ (((lc3 >> 1) & 3) << 4));
  char* wx0 = (char*)&Xs[0] + t * 16;
  const char* zl = (const char*)&zls[0];
  const bool mL = (l15 == 0);
  const bool mR = (l15 == 15);

  f32x4 acc[8][4];
#pragma unroll
  for (int m = 0; m < 8; ++m)
#pragma unroll
    for (int n = 0; n < 4; ++n)
      acc[m][n] = (f32x4){0.f, 0.f, 0.f, 0.f};

  bf16x8 fa0[8], fb0[4], fa1[8], fb1[4];

#define LD8(p) (*reinterpret_cast<const bf16x8*>(p))

#define LOAD_A(FA, tpn)                                                  \
  { _Pragma("unroll") for (int m_ = 0; m_ < 8; ++m_)                     \
      FA[m_] = LD8(paR[(tpn) & 3] + m_ * 1024); }

#define LOAD_B(FB, tpn)                                                  \
  { const int dy_ = (tpn) / 3 - 1, dx_ = (tpn) % 3 - 1;                  \
    const int rbo_ = (wc + dy_ + 1) * 4096;                              \
    const char* qq_ = (dx_ == -1) ? q0 : ((dx_ == 0) ? q1 : q2);         \
    const char* s0_ = (dx_ == -1 && mL) ? (zl - rbo_) : qq_;             \
    const char* s3_ = (dx_ == 1) ? (mR ? (zl - rbo_ - 3072) : q3) : qq_; \
    FB[0] = LD8(s0_ + rbo_);                                             \
    FB[1] = LD8(qq_ + rbo_ + 1024);                                      \
    FB[2] = LD8(qq_ + rbo_ + 2048);                                      \
    FB[3] = LD8(s3_ + rbo_ + 3072); }

#define MFMA32(CA, CB)                                                   \
  { __builtin_amdgcn_s_setprio(1);                                       \
    _Pragma("unroll") for (int m_ = 0; m_ < 8; ++m_)                     \
      _Pragma("unroll") for (int n_ = 0; n_ < 4; ++n_)                   \
        acc[m_][n_] = __builtin_amdgcn_mfma_f32_16x16x32_bf16(           \
            CA[m_], CB[n_], acc[m_][n_], 0, 0, 0);                       \
    __builtin_amdgcn_s_setprio(0); }

#define DO_TAP(tp, CA, CB, NA, NB_)                                      \
  { const int pan_ = chBase + ((tp) >= 6 ? advA : 0) +                   \
                     (((tp) + 3) % 9) * 16384;                           \
    gl_lds16(aS0 + pan_, waR[((tp) + 3) & 3]);                           \
    gl_lds16(aS1 + pan_, waR[((tp) + 3) & 3] + 8192); }                  \
  if ((tp) == 7) {                                                       \
    _Pragma("unroll") for (int i_ = 0; i_ < 3; ++i_)                     \
        gl_lds16(xS[i_] + knv, wxT + i_ * 8192);                         \
  }                                                                      \
  if ((tp) < 8) {                                                        \
    LOAD_A(NA, (tp) + 1)                                                 \
    LOAD_B(NB_, (tp) + 1)                                                \
    asm volatile("s_waitcnt lgkmcnt(12)" ::: "memory");                  \
  } else {                                                               \
    LOAD_A(NA, 9)                                                        \
    asm volatile("s_waitcnt lgkmcnt(8)" ::: "memory");                   \
  }                                                                      \
  __builtin_amdgcn_sched_barrier(0);                                     \
  MFMA32(CA, CB)                                                         \
  if ((tp) == 7) { asm volatile("s_waitcnt vmcnt(5)" ::: "memory"); }    \
  else { asm volatile("s_waitcnt vmcnt(2)" ::: "memory"); }              \
  __builtin_amdgcn_s_barrier();                                          \
  asm volatile("" ::: "memory");

#define RUN_CHUNK(FAS, FBS, FAO, FBO)                                    \
  LOAD_B(FBS, 0)                                                         \
  DO_TAP(0, FAS, FBS, FAO, FBO)                                          \
  DO_TAP(1, FAO, FBO, FAS, FBS)                                          \
  DO_TAP(2, FAS, FBS, FAO, FBO)                                          \
  DO_TAP(3, FAO, FBO, FAS, FBS)                                          \
  DO_TAP(4, FAS, FBS, FAO, FBO)                                          \
  DO_TAP(5, FAO, FBO, FAS, FBS)                                          \
  DO_TAP(6, FAS, FBS, FAO, FBO)                                          \
  DO_TAP(7, FAO, FBO, FAS, FBS)                                          \
  DO_TAP(8, FAS, FBS, FAO, FBO)

#define ROT_RING()                                                       \
  { const char* tA_ = paR[0];                                            \
    paR[0] = paR[1]; paR[1] = paR[2]; paR[2] = paR[3]; paR[3] = tA_;     \
    char* tW_ = waR[0];                                                  \
    waR[0] = waR[1]; waR[1] = waR[2]; waR[2] = waR[3]; waR[3] = tW_;     \
    chBase += 9 * 16384; xb ^= 24576; }

  // ---- prologue: A panels 0,1,2 + X chunk 0; drain; preload A frags tap0 ----
#pragma unroll
  for (int i = 0; i < 3; ++i)
    gl_lds16(xS[i], wx0 + i * 8192);
#pragma unroll
  for (int s = 0; s < 3; ++s) {
    gl_lds16(aS0 + s * 16384, waR[s]);
    gl_lds16(aS1 + s * 16384, waR[s] + 8192);
  }
  asm volatile("s_waitcnt vmcnt(0) lgkmcnt(0)" ::: "memory");
  __builtin_amdgcn_s_barrier();
  asm volatile("" ::: "memory");
  LOAD_A(fa0, 0)

  int chBase = 0;
  uint32_t xb = 0;

  for (int c2 = 0; c2 < 8; ++c2) {
    {  // chunk 2*c2 (starts on fa0/fb0)
      const int advA = 9 * 16384;
      const int knv = (2 * c2 + 1) * 32;
      const char* q0 = pbx[0] + xb;
      const char* q1 = pbx[1] + xb;
      const char* q2 = pbx[2] + xb;
      const char* q3 = pbx3 + xb;
      char* wxT = wx0 + (xb ^ 24576);
      RUN_CHUNK(fa0, fb0, fa1, fb1)
      ROT_RING()
    }
    {  // chunk 2*c2+1 (starts on fa1/fb1)
      const int advA = (c2 < 7) ? 9 * 16384 : 0;
      const int knv = (c2 < 7) ? (2 * c2 + 2) * 32 : 0;
      const char* q0 = pbx[0] + xb;
      const char* q1 = pbx[1] + xb;
      const char* q2 = pbx[2] + xb;
      const char* q3 = pbx3 + xb;
      char* wxT = wx0 + (xb ^ 24576);
      RUN_CHUNK(fa1, fb1, fa0, fb0)
      ROT_RING()
    }
  }
#undef ROT_RING
#undef RUN_CHUNK
#undef DO_TAP
#undef MFMA32
#undef LOAD_B
#undef LOAD_A
#undef LD8

  asm volatile("s_waitcnt vmcnt(0)" ::: "memory");
  __builtin_amdgcn_s_barrier();

  // ---- epilogue: out = d[b,o] * acc ----
#pragma unroll
  for (int m = 0; m < 8; ++m) {
#pragma unroll
    for (int n = 0; n < 4; ++n) {
#pragma unroll
      for (int j = 0; j < 4; ++j) {
        int o_l = wr * 128 + m * 16 + (lane >> 4) * 4 + j;
        int o = ot * 256 + o_l;
        int yy = sp * 4 + wc;
        int cx = n * 16 + l15;
        out[(((size_t)b * COUT + o) * HH + yy) * WW + cx] = d_s[o_l] * acc[m][n][j];
      }
    }
  }
}

// ---------------- fallback conv (round-1 kernel) for small ws ----------------
__global__ __launch_bounds__(256) void k_conv_fb(const float* __restrict__ x,
                                                 const short* __restrict__ Wr,
                                                 const float* __restrict__ gamma,
                                                 const float* __restrict__ dscale,
                                                 float* __restrict__ out) {
  __shared__ short As[128 * 64];
  __shared__ short Xs[4 * 64 * 64];
  __shared__ float gam_s[CIN];
  __shared__ float d_s[128];

  const int sp = blockIdx.x;
  const int ot = blockIdx.y;
  const int b  = blockIdx.z;
  const int t  = threadIdx.x;
  const int lane = t & 63;
  const int wv = t >> 6;
  const int wr = wv >> 1;
  const int wc = wv & 1;

  gam_s[t] = gamma[b * CIN + t];
  gam_s[t + 256] = gamma[b * CIN + t + 256];
  if (t < 128) d_s[t] = dscale[b * COUT + ot * 128 + t];

  f32x4 acc[4][4];
#pragma unroll
  for (int m = 0; m < 4; ++m)
#pragma unroll
    for (int n = 0; n < 4; ++n)
      acc[m][n] = (f32x4){0.f, 0.f, 0.f, 0.f};

  const int srow = t >> 6;
  const int sc = t & 63;
  const int ysrc = sp * 2 + srow - 1;
  const bool rv = (ysrc >= 0) && (ysrc < HH);
  const int ycl = rv ? ysrc : 0;
  const float* xrow = x + (((size_t)b * CIN) * HH + ycl) * WW + sc;
  short* xs_base = &Xs[(srow * 64 + sc) * 64];
  const int xs_sw = (sc & 7) << 4;

  for (int chunk = 0; chunk < CIN / 64; ++chunk) {
    const int i0 = chunk * 64;
    __syncthreads();
    {
      const float* xp = xrow + (size_t)i0 * (HH * WW);
#pragma unroll
      for (int i8 = 0; i8 < 8; ++i8) {
        short tmp[8];
#pragma unroll
        for (int j = 0; j < 8; ++j) {
          int i = i8 * 8 + j;
          float v = rv ? xp[i * (HH * WW)] : 0.0f;
          tmp[j] = f2bf(v * gam_s[i0 + i]);
        }
        char* dst = (char*)xs_base + ((i8 * 16) ^ xs_sw);
        *reinterpret_cast<bf16x8*>(dst) = *reinterpret_cast<const bf16x8*>(tmp);
      }
    }
    for (int tap = 0; tap < TAPS; ++tap) {
      __syncthreads();
#pragma unroll
      for (int j = 0; j < 4; ++j) {
        int s = t + 256 * j;
        int row = s >> 3, sl = s & 7;
        int kbyte = (sl * 16) ^ ((row & 7) << 4);
        const short* src = Wr + ((size_t)(ot * 128 + row) * TAPS + tap) * CIN +
                           i0 + (kbyte >> 1);
        *reinterpret_cast<bf16x8*>((char*)As + row * 128 + sl * 16) =
            *reinterpret_cast<const bf16x8*>(src);
      }
      __syncthreads();

      const int dy = tap / 3 - 1, dx = tap % 3 - 1;
      bf16x8 afr[2][4], bfr[2][4];
#pragma unroll
      for (int kk = 0; kk < 2; ++kk) {
        const int kb = kk * 64 + (lane >> 4) * 16;
#pragma unroll
        for (int m = 0; m < 4; ++m) {
          int row = wr * 64 + m * 16 + (lane & 15);
          afr[kk][m] = *reinterpret_cast<const bf16x8*>(
              (const char*)As + row * 128 + (kb ^ ((row & 7) << 4)));
        }
#pragma unroll
        for (int n = 0; n < 4; ++n) {
          int p = wc * 64 + n * 16 + (lane & 15);
          int r = p >> 6, c = p & 63;
          int cc = c + dx;
          bool val = (cc >= 0) && (cc < WW);
          int ccl = val ? cc : 0;
          int rr = r + dy + 1;
          bf16x8 f = *reinterpret_cast<const bf16x8*>(
              (const char*)Xs + (rr * 64 + ccl) * 128 + (kb ^ ((ccl & 7) << 4)));
          if (!val) f = (bf16x8){0, 0, 0, 0, 0, 0, 0, 0};
          bfr[kk][n] = f;
        }
      }
#pragma unroll
      for (int m = 0; m < 4; ++m)
#pragma unroll
        for (int n = 0; n < 4; ++n)
#pragma unroll
          for (int kk = 0; kk < 2; ++kk)
            acc[m][n] = __builtin_amdgcn_mfma_f32_16x16x32_bf16(
                afr[kk][m], bfr[kk][n], acc[m][n], 0, 0, 0);
    }
  }

#pragma unroll
  for (int m = 0; m < 4; ++m) {
#pragma unroll
    for (int n = 0; n < 4; ++n) {
#pragma unroll
      for (int j = 0; j < 4; ++j) {
        int o_l = wr * 64 + m * 16 + (lane >> 4) * 4 + j;
        int o = ot * 128 + o_l;
        int p = wc * 64 + n * 16 + (lane & 15);
        int yy = sp * 2 + (p >> 6);
        int cx = p & 63;
        out[(((size_t)b * COUT + o) * HH + yy) * WW + cx] = d_s[o_l] * acc[m][n][j];
      }
    }
  }
}

extern "C" void kernel_launch(void* const* d_in, const int* in_sizes, int n_in,
                              void* d_out, int out_size, void* d_ws, size_t ws_size,
                              hipStream_t stream) {
  const float* x = (const float*)d_in[0];
  const float* y = (const float*)d_in[1];
  const float* w_conv = (const float*)d_in[2];
  const float* w_gamma = (const float*)d_in[3];
  const float* b_gamma = (const float*)d_in[4];
  float* out = (float*)d_out;

  char* ws = (char*)d_ws;
  short* W2 = (short*)ws;                        // 4,718,592 B (+pad)
  float* gamma = (float*)(ws + 4849664);         // 32,768 B
  float* dsc = (float*)(ws + 4882432);           // 32,768 B
  float* s2 = (float*)(ws + 4915200);            // 1,048,576 B
  char* zbuf = ws + 5963776;                     // 4,096 B zero page
  short* xm = (short*)(ws + 5967872);            // 67,108,864 B
  const size_t NEED = 5967872 + (size_t)NB * HH * WW * CIN * 2 + 4096;

  const bool fast = ws_size >= NEED;

  if (fast) {
    hipLaunchKernelGGL(k_prep2, dim3(COUT), dim3(256), 0, stream, w_conv, s2, W2);
    hipLaunchKernelGGL(k_gd, dim3(NB), dim3(512), 0, stream, y, w_gamma, b_gamma,
                       s2, gamma, dsc, (float*)zbuf);
    hipLaunchKernelGGL(k_xmod2, dim3(HH, NB), dim3(256), 0, stream, x, gamma, xm);
    hipLaunchKernelGGL(k_conv10, dim3(512), dim3(512), 0, stream, xm, W2,
                       (const short*)zbuf, dsc, out);
  } else {
    hipLaunchKernelGGL(k_gamma, dim3(NB), dim3(512), 0, stream, y, w_gamma,
                       b_gamma, gamma, (float*)nullptr);
    hipLaunchKernelGGL(k_prep, dim3(COUT), dim3(256), 0, stream, w_conv, s2, W2);
    hipLaunchKernelGGL(k_d, dim3(NB), dim3(512), 0, stream, gamma, s2, dsc);
    hipLaunchKernelGGL(k_conv_fb, dim3(32, 4, NB), dim3(256), 0, stream, x, W2,
                       gamma, dsc, out);
  }
}